// Round 1
// baseline (232.971 us; speedup 1.0000x reference)
//
#include <hip/hip_runtime.h>
#include <stdint.h>

// CIN forward, MI355X. R8 = R7 restructured for occupancy:
//   1 batch/block, 8 waves x 1 o-tile (full K) each, grid 1024.
//   Per-wave regs: acc 16 + wbuf 16 + xf 16 + hv 8 + addr  (~71 unified)
//   LDS 17.4 KB  ->  3 blocks/CU = 24 waves/CU (was 16).
// Cost: B-frag build duplicated 8x/batch (was 4x) -- VALU demand ~+14%,
// still far under the MFMA floor. Inner loop pipeline identical to R7
// (depth-2 consume-then-reload rotation, hv double-buffer, sched_barrier
// pins). 16x16x32 f16 MFMA; single coalesced pack kernel unchanged.

typedef __attribute__((ext_vector_type(8))) _Float16 f16x8;
typedef __attribute__((ext_vector_type(2))) _Float16 f16x2;
typedef __attribute__((ext_vector_type(4))) float f32x4;
typedef __attribute__((ext_vector_type(4))) int i32x4;

union AB {
  i32x4 i;
  f16x8 h;
  uint32_t u[4];
};

static __device__ __forceinline__ uint32_t pkmul(uint32_t a, uint32_t b) {
  f16x2 r = __builtin_bit_cast(f16x2, a) * __builtin_bit_cast(f16x2, b);
  return __builtin_bit_cast(uint32_t, r);  // one v_pk_mul_f16
}
static __device__ __forceinline__ uint32_t pkcvt(float a, float b) {
  return __builtin_bit_cast(uint32_t, __builtin_amdgcn_cvt_pkrtz(a, b));
}

#define HP 136  // hT row: 128 ch + 8 pad (272B stride: 16B-aligned, 2-way banks)

__global__ __launch_bounds__(512, 6) void cin_main(
    const float* __restrict__ x, const uint16_t* __restrict__ wp,
    const float* __restrict__ bias0, const float* __restrict__ bias1,
    const float* __restrict__ bias2, float* __restrict__ out) {
  __shared__ __align__(16) uint16_t hT[64][HP];  // [d][chan] fp16, one batch

  const int tid = threadIdx.x;
  const int w = tid >> 6, lane = tid & 63;  // w = o-tile index (0..7)
  const int q = lane >> 4;   // k-quad: B row k = q*8+j; C row o = q*4+r
  const int i = lane & 15;   // d within tile (B/C col); A row o (mod 16)
  const int b = blockIdx.x;  // one batch per block

  // ---- stage x -> hT[d][m] fp16 (layer-0 h == x; 32 channels)
  for (int e = tid; e < 2048; e += 512) {
    int m = e >> 6, d = e & 63;
    hT[d][m] =
        __builtin_bit_cast(uint16_t, (_Float16)x[(size_t)b * 2048 + m * 64 + d]);
  }
  __syncthreads();

  // ---- x B-frags (loop-invariant): xf[t].j = x[m=q*8+j][d=t*16+i]
  AB xf[4];
#pragma unroll
  for (int t = 0; t < 4; ++t)
    xf[t].i = *(const i32x4*)&hT[t * 16 + i][q * 8];  // ds_read_b128

  f32x4 acc[4];  // [t] : 4 independent chains, one o-tile

#pragma unroll
  for (int L = 0; L < 3; ++L) {
    const int Kch = (L == 0) ? 32 : 128;
    const uint16_t* wl = (L == 0) ? wp : (L == 1) ? wp + 131072 : wp + 655360;
    const float* bias = (L == 0) ? bias0 : (L == 1) ? bias1 : bias2;

    // packed W frag elems: (ot*Kch + c)*512 + lane*8 ; this wave's ot = w
    const uint16_t* wptr = wl + (size_t)w * Kch * 512 + lane * 8;

#pragma unroll
    for (int t = 0; t < 4; ++t) acc[t] = (f32x4){0.f, 0.f, 0.f, 0.f};

    AB wbuf[2][2];  // [slot][cc] : 16 VGPRs, depth-2 rotation
    uint32_t hvA[4], hvB[4];

    auto loadSlot = [&](int s, int c) {
      int cw = (c < Kch) ? c : 0;  // wrap: harmless dummy reload
#pragma unroll
      for (int cc = 0; cc < 2; ++cc)
        wbuf[s][cc].i = *(const i32x4*)(wptr + (size_t)(cw + cc) * 512);
    };
    auto loadHv = [&](uint32_t (&hv)[4], int c) {
      int cw = (c < Kch) ? c : 0;
#pragma unroll
      for (int t = 0; t < 4; ++t)
        hv[t] = *(const uint32_t*)&hT[t * 16 + i][cw];  // channels cw, cw+1
    };
    auto computePair = [&](const AB (&wb)[2], const uint32_t (&hv)[4]) {
#pragma unroll
      for (int cc = 0; cc < 2; ++cc)
#pragma unroll
        for (int t = 0; t < 4; ++t) {
          uint32_t hd = __builtin_amdgcn_perm(hv[t], hv[t],
                                              cc ? 0x03020302u : 0x01000100u);
          AB bf;  // B-frag: P[c*32 + q*8+j][d] = h[c,d] * x[q*8+j,d]
#pragma unroll
          for (int k = 0; k < 4; ++k) bf.u[k] = pkmul(hd, xf[t].u[k]);
          acc[t] = __builtin_amdgcn_mfma_f32_16x16x32_f16(wb[cc].h, bf.h,
                                                          acc[t], 0, 0, 0);
        }
    };

    // prologue: slots hold pairs 0 and 2; hvA holds pair 0
    loadSlot(0, 0);
    loadSlot(1, 2);
    loadHv(hvA, 0);

#pragma unroll 1
    for (int c0 = 0; c0 < Kch; c0 += 4) {
      loadHv(hvB, c0 + 2);            // LDS prefetch for pair c0+2
      computePair(wbuf[0], hvA);      // consume pair c0 ...
      loadSlot(0, c0 + 4);            // ... THEN reload slot 0 (pair c0+4)
      __builtin_amdgcn_sched_barrier(0);  // pin load issue here
      loadHv(hvA, c0 + 4);
      computePair(wbuf[1], hvB);      // consume pair c0+2 ...
      loadSlot(1, c0 + 6);            // ... THEN reload slot 1 (pair c0+6)
      __builtin_amdgcn_sched_barrier(0);
    }

    // ---- bias + ReLU (C layout: o = w*16 + q*4 + r, d = t*16 + i)
    f32x4 bv = *(const f32x4*)(bias + w * 16 + q * 4);
#pragma unroll
    for (int t = 0; t < 4; ++t)
#pragma unroll
      for (int r = 0; r < 4; ++r)
        acc[t][r] = fmaxf(acc[t][r] + bv[r], 0.f);

    if (L < 2) {
      __syncthreads();  // all waves done READING hT before overwrite
#pragma unroll
      for (int t = 0; t < 4; ++t) {
        uint2 pk;  // next-layer h channels o = w*16 + q*4 + r
        pk.x = pkcvt(acc[t][0], acc[t][1]);
        pk.y = pkcvt(acc[t][2], acc[t][3]);
        *(uint2*)&hT[t * 16 + i][w * 16 + q * 4] = pk;
      }
    }

    // d-sum: in-register over t, then xor-shuffle the 16 i-lanes
#pragma unroll
    for (int r = 0; r < 4; ++r) {
      float s = acc[0][r] + acc[1][r] + acc[2][r] + acc[3][r];
      s += __shfl_xor(s, 1);
      s += __shfl_xor(s, 2);
      s += __shfl_xor(s, 4);
      s += __shfl_xor(s, 8);
      if (i == 0)
        out[(size_t)b * 384 + L * 128 + w * 16 + q * 4 + r] = s;
    }

    if (L < 2) __syncthreads();  // hT writes visible before next K-loop
  }
}

// One pack kernel for all 3 layers. Reads coalesced along k (thread = (o,kq),
// 8 consecutive floats); writes fp16 frags: dst elem (ot*Kch+c)*512 + q*128 + i*8
// == (ot*Kch+c)*512 + lane*8 with lane = q*16+i (layout unchanged from R3/R7,
// which passed correctness).
__global__ void pack_w_all(const float* __restrict__ W0, const float* __restrict__ W1,
                           const float* __restrict__ W2, uint16_t* __restrict__ Wp) {
  int blk = blockIdx.x;
  const float* W;
  uint16_t* dst;
  int kshift;
  if (blk < 64)       { W = W0; dst = Wp;          kshift = 5; }
  else if (blk < 320) { W = W1; dst = Wp + 131072; kshift = 7; blk -= 64; }
  else                { W = W2; dst = Wp + 655360; kshift = 7; blk -= 320; }
  int idx = blk * 256 + threadIdx.x;
  int Kq = 1 << (kshift + 2);        // Kch*4 = K/8
  int o = idx >> (kshift + 2);
  int kq = idx & (Kq - 1);
  int c = kq >> 2, q = kq & 3;
  int ot = o >> 4, ii = o & 15;
  const float* src = W + ((size_t)o << (kshift + 5)) + kq * 8;
  uint4 val;
  val.x = pkcvt(src[0], src[1]);
  val.y = pkcvt(src[2], src[3]);
  val.z = pkcvt(src[4], src[5]);
  val.w = pkcvt(src[6], src[7]);
  *(uint4*)(dst + ((((size_t)ot << kshift) + c) << 9) + (q << 7) + (ii << 3)) = val;
}

extern "C" void kernel_launch(void* const* d_in, const int* in_sizes, int n_in,
                              void* d_out, int out_size, void* d_ws, size_t ws_size,
                              hipStream_t stream) {
  (void)in_sizes; (void)n_in; (void)out_size; (void)ws_size;
  const float* x  = (const float*)d_in[0];
  const float* W0 = (const float*)d_in[1];
  const float* b0 = (const float*)d_in[2];
  const float* W1 = (const float*)d_in[3];
  const float* b1 = (const float*)d_in[4];
  const float* W2 = (const float*)d_in[5];
  const float* b2 = (const float*)d_in[6];
  uint16_t* wpacked = (uint16_t*)d_ws;  // 2.25 MB of ws

  hipLaunchKernelGGL(pack_w_all, dim3(576), dim3(256), 0, stream, W0, W1, W2, wpacked);
  hipLaunchKernelGGL(cin_main, dim3(1024), dim3(512), 0, stream,
                     x, wpacked, b0, b1, b2, (float*)d_out);
}

// Round 2
// 214.772 us; speedup vs baseline: 1.0847x; 1.0847x over previous
//
#include <hip/hip_runtime.h>
#include <stdint.h>

// CIN forward, MI355X. R9: switch 16x16x32 -> 32x32x16 f16 MFMA.
// Rationale (R7/R8 counters): wall tracks per-wave VALU+MFMA serial demand;
// B-frag build is ~5 VALU insts per 16B operand fragment regardless of shape,
// so the 2x-FLOP 32x32x16 halves VALU/FLOP (ratio 1.0 -> 0.28) and halves
// W bytes/FLOP. Wave = 1 o-tile(32) x 2 d-tiles(32), 4 waves/batch,
// 256-thr blocks, grid 1024 (4 blocks/CU = 16 waves/CU). W read once/batch
// (D=1, ~26 TB/s L2 at target). Depth-2 consume-then-reload W rotation +
// hv double-buffer kept from R7. acc 32 + wbuf 32 + xf 16 regs.

typedef __attribute__((ext_vector_type(8))) _Float16 f16x8;
typedef __attribute__((ext_vector_type(2))) _Float16 f16x2;
typedef __attribute__((ext_vector_type(4))) float f32x4;
typedef __attribute__((ext_vector_type(16))) float f32x16;
typedef __attribute__((ext_vector_type(4))) int i32x4;

union AB {
  i32x4 i;
  f16x8 h;
  uint32_t u[4];
};

static __device__ __forceinline__ uint32_t pkmul(uint32_t a, uint32_t b) {
  f16x2 r = __builtin_bit_cast(f16x2, a) * __builtin_bit_cast(f16x2, b);
  return __builtin_bit_cast(uint32_t, r);  // one v_pk_mul_f16
}
static __device__ __forceinline__ uint32_t pkcvt(float a, float b) {
  return __builtin_bit_cast(uint32_t, __builtin_amdgcn_cvt_pkrtz(a, b));
}

#define HP 136  // hT row: 128 ch + 8 pad (272B stride: 16B-aligned)

__global__ __launch_bounds__(256, 4) void cin_main(
    const float* __restrict__ x, const uint16_t* __restrict__ wp,
    const float* __restrict__ bias0, const float* __restrict__ bias1,
    const float* __restrict__ bias2, float* __restrict__ out) {
  __shared__ __align__(16) uint16_t hT[64][HP];  // [d][chan] fp16, one batch

  const int tid = threadIdx.x;
  const int ot = tid >> 6, lane = tid & 63;  // wave = o-tile index (0..3)
  const int hi = lane >> 5;   // A/B k-half; C row bit (4*hi)
  const int l31 = lane & 31;  // A row (o mod 32); B/C col (d mod 32)
  const int b = blockIdx.x;   // one batch per block

  // ---- stage x -> hT[d][m] fp16 (layer-0 h == x; 32 channels)
  for (int e = tid; e < 2048; e += 256) {
    int m = e >> 6, d = e & 63;
    hT[d][m] =
        __builtin_bit_cast(uint16_t, (_Float16)x[(size_t)b * 2048 + m * 64 + d]);
  }
  __syncthreads();

  // ---- x B-frags (loop-invariant): xf[dt][s].j = x[m=s*16+hi*8+j][d=dt*32+l31]
  AB xf[2][2];
#pragma unroll
  for (int dt = 0; dt < 2; ++dt)
#pragma unroll
    for (int s = 0; s < 2; ++s)
      xf[dt][s].i = *(const i32x4*)&hT[dt * 32 + l31][s * 16 + hi * 8];

  f32x16 acc0, acc1;  // d-tiles 0 (d=l31) and 1 (d=32+l31)

#pragma unroll
  for (int L = 0; L < 3; ++L) {
    const int Kch = (L == 0) ? 32 : 128;
    const uint16_t* wl = (L == 0) ? wp : (L == 1) ? wp + 131072 : wp + 655360;
    const float* bias = (L == 0) ? bias0 : (L == 1) ? bias1 : bias2;

    // packed W frag for (c,s): wl + ((ot*Kch + c)*2 + s)*512 + lane*8
    const uint16_t* wptr = wl + (size_t)ot * Kch * 1024 + lane * 8;

#pragma unroll
    for (int r = 0; r < 16; ++r) { acc0[r] = 0.f; acc1[r] = 0.f; }

    AB wbuf[2][4];  // [slot][cc*2+s] : 32 VGPRs, depth-2 rotation
    uint32_t hvA[2], hvB[2];

    auto loadSlot = [&](int sl, int c) {
      int cw = (c < Kch) ? c : 0;  // wrap: harmless dummy reload
#pragma unroll
      for (int cc = 0; cc < 2; ++cc)
#pragma unroll
        for (int s = 0; s < 2; ++s)
          wbuf[sl][cc * 2 + s].i =
              *(const i32x4*)(wptr + (size_t)(cw + cc) * 1024 + s * 512);
    };
    auto loadHv = [&](uint32_t (&hv)[2], int c) {
      int cw = (c < Kch) ? c : 0;
#pragma unroll
      for (int dt = 0; dt < 2; ++dt)
        hv[dt] = *(const uint32_t*)&hT[dt * 32 + l31][cw];  // ch cw, cw+1
    };
    // one step = 2 channels (cc=0,1) x 2 k-slices (s) x 2 d-tiles = 8 MFMAs
    auto computeStep = [&](const AB (&wb)[4], const uint32_t (&hv)[2]) {
#pragma unroll
      for (int cc = 0; cc < 2; ++cc) {
        uint32_t hd0 = __builtin_amdgcn_perm(hv[0], hv[0],
                                             cc ? 0x03020302u : 0x01000100u);
        uint32_t hd1 = __builtin_amdgcn_perm(hv[1], hv[1],
                                             cc ? 0x03020302u : 0x01000100u);
#pragma unroll
        for (int s = 0; s < 2; ++s) {
          AB bf0, bf1;  // B: P[k=(c+cc)*32+s*16+hi*8+j][d] = h[c+cc,d]*x[m,d]
#pragma unroll
          for (int k = 0; k < 4; ++k) {
            bf0.u[k] = pkmul(hd0, xf[0][s].u[k]);
            bf1.u[k] = pkmul(hd1, xf[1][s].u[k]);
          }
          acc0 = __builtin_amdgcn_mfma_f32_32x32x16_f16(wb[cc * 2 + s].h,
                                                        bf0.h, acc0, 0, 0, 0);
          acc1 = __builtin_amdgcn_mfma_f32_32x32x16_f16(wb[cc * 2 + s].h,
                                                        bf1.h, acc1, 0, 0, 0);
        }
      }
    };

    // prologue: slots hold channel-pairs 0 and 2; hvA holds pair 0
    loadSlot(0, 0);
    loadSlot(1, 2);
    loadHv(hvA, 0);

#pragma unroll 1
    for (int c0 = 0; c0 < Kch; c0 += 4) {
      loadHv(hvB, c0 + 2);            // LDS prefetch for pair c0+2
      computeStep(wbuf[0], hvA);      // consume pair c0 ...
      loadSlot(0, c0 + 4);            // ... THEN reload slot 0 (pair c0+4)
      __builtin_amdgcn_sched_barrier(0);  // pin load issue here
      loadHv(hvA, c0 + 4);
      computeStep(wbuf[1], hvB);      // consume pair c0+2 ...
      loadSlot(1, c0 + 6);            // ... THEN reload slot 1 (pair c0+6)
      __builtin_amdgcn_sched_barrier(0);
    }

    // ---- bias + ReLU. C layout (32x32): col d = dt*32 + l31,
    // row o = ot*32 + (r&3) + 8*(r>>2) + 4*hi
    f32x4 bv[4];
#pragma unroll
    for (int rg = 0; rg < 4; ++rg)
      bv[rg] = *(const f32x4*)(bias + ot * 32 + 8 * rg + 4 * hi);
#pragma unroll
    for (int r = 0; r < 16; ++r) {
      acc0[r] = fmaxf(acc0[r] + bv[r >> 2][r & 3], 0.f);
      acc1[r] = fmaxf(acc1[r] + bv[r >> 2][r & 3], 0.f);
    }

    if (L < 2) {
      __syncthreads();  // all waves done READING hT before overwrite
#pragma unroll
      for (int rg = 0; rg < 4; ++rg) {
        uint2 pk0, pk1;  // next-layer h channels, 4 consecutive rows
        pk0.x = pkcvt(acc0[4 * rg + 0], acc0[4 * rg + 1]);
        pk0.y = pkcvt(acc0[4 * rg + 2], acc0[4 * rg + 3]);
        pk1.x = pkcvt(acc1[4 * rg + 0], acc1[4 * rg + 1]);
        pk1.y = pkcvt(acc1[4 * rg + 2], acc1[4 * rg + 3]);
        int ch = ot * 32 + 8 * rg + 4 * hi;
        *(uint2*)&hT[l31][ch] = pk0;
        *(uint2*)&hT[32 + l31][ch] = pk1;
      }
    }

    // ---- d-sum: acc0+acc1 (d and d+32), then xor-reduce the 32 l31 lanes
#pragma unroll
    for (int rg = 0; rg < 4; ++rg) {
      f32x4 s4;
#pragma unroll
      for (int rr = 0; rr < 4; ++rr) {
        float s = acc0[4 * rg + rr] + acc1[4 * rg + rr];
        s += __shfl_xor(s, 1);
        s += __shfl_xor(s, 2);
        s += __shfl_xor(s, 4);
        s += __shfl_xor(s, 8);
        s += __shfl_xor(s, 16);
        s4[rr] = s;
      }
      if (l31 == 0)
        *(f32x4*)(out + (size_t)b * 384 + L * 128 + ot * 32 + 8 * rg + 4 * hi) = s4;
    }

    if (L < 2) __syncthreads();  // hT writes visible before next K-loop
  }
}

// Pack for 32x32x16 A layout: frag (ot,c,s) elem lane*8+j holds
// W[o = ot*32 + (lane&31)][k = c*32 + s*16 + (lane>>5)*8 + j].
// Reads stay coalesced along k (thread = (o,kq), 8 consecutive floats).
__global__ void pack_w_all(const float* __restrict__ W0, const float* __restrict__ W1,
                           const float* __restrict__ W2, uint16_t* __restrict__ Wp) {
  int blk = blockIdx.x;
  const float* W;
  uint16_t* dst;
  int kshift;  // Kch = 1<<kshift, K = 1<<(kshift+5)
  if (blk < 64)       { W = W0; dst = Wp;          kshift = 5; }
  else if (blk < 320) { W = W1; dst = Wp + 131072; kshift = 7; blk -= 64; }
  else                { W = W2; dst = Wp + 655360; kshift = 7; blk -= 320; }
  int idx = blk * 256 + threadIdx.x;
  int Kq = 1 << (kshift + 2);        // K/8
  int o = idx >> (kshift + 2);
  int kq = idx & (Kq - 1);
  int c = kq >> 2, s = (kq >> 1) & 1, hi = kq & 1;
  int ot = o >> 5, li = o & 31;
  const float* src = W + ((size_t)o << (kshift + 5)) + kq * 8;
  uint4 val;
  val.x = pkcvt(src[0], src[1]);
  val.y = pkcvt(src[2], src[3]);
  val.z = pkcvt(src[4], src[5]);
  val.w = pkcvt(src[6], src[7]);
  size_t d16 = ((((size_t)(ot << kshift) + c) * 2 + s) << 9) + (hi << 8) + (li << 3);
  *(uint4*)(dst + d16) = val;
}

extern "C" void kernel_launch(void* const* d_in, const int* in_sizes, int n_in,
                              void* d_out, int out_size, void* d_ws, size_t ws_size,
                              hipStream_t stream) {
  (void)in_sizes; (void)n_in; (void)out_size; (void)ws_size;
  const float* x  = (const float*)d_in[0];
  const float* W0 = (const float*)d_in[1];
  const float* b0 = (const float*)d_in[2];
  const float* W1 = (const float*)d_in[3];
  const float* b1 = (const float*)d_in[4];
  const float* W2 = (const float*)d_in[5];
  const float* b2 = (const float*)d_in[6];
  uint16_t* wpacked = (uint16_t*)d_ws;  // 2.25 MB of ws

  hipLaunchKernelGGL(pack_w_all, dim3(576), dim3(256), 0, stream, W0, W1, W2, wpacked);
  hipLaunchKernelGGL(cin_main, dim3(1024), dim3(256), 0, stream,
                     x, wpacked, b0, b1, b2, (float*)d_out);
}